// Round 16
// baseline (754.665 us; speedup 1.0000x reference)
//
#include <hip/hip_runtime.h>
#include <stdint.h>

#define NCLS 80
#define NKER 256
#define STOT 3872
#define NFLAT (STOT*NCLS)   // 309760
#define NPRE 500
#define NPREP 512
#define MAXI 100
#define MH 160
#define MW 240
#define MP (MH*MW)          // 38400
#define OH 640
#define OW 960
#define NWORD 600           // 38400/64
#define PARTW 300           // 38400/128
#define UCAP 131072
#define TAU 1e-3f

// ---- workspace byte offsets ----
#define WS_HIST   0u          // 65536 u32 = 262144
#define WS_META   262144u     // counters: [0]=cand count, [2]=npair, [3]=ulist count
#define WS_CMP    266240u     // 512 u64 compS bits
#define WS_CORR   270336u     // 512 f64 wsum corrections
#define WS_ZEROB  274432u     // memset range [0, WS_ZEROB)
#define WS_PIOU   274432u     // 124750 f64 pair iou -> ends 1,272,432
#define WS_CANDV  1272432u    // 4096 f32
#define WS_CANDI  1288816u    // 4096 i32
#define WS_FLAT   2266240u    // plist region (499KB)
#define WS_KP     2790528u    // 512*256 f32 row-major kp = 524,288
#define WS_SEL    3538048u    // arrays x 4096B
#define WS_MB     4115584u    // 500*600 u64 = 2,400,000
#define WS_PART   6515584u    // 500*300 f64 = 1,200,000
#define WS_SEG    7715584u    // 500*38400 u16 (bf16) -> ends 46,115,584
#define WS_ULIST  46115584u   // 131072 u32 = 524,288
#define WS_UZ     46639872u   // 131072 f32 = 524,288 -> ends 47,164,160
#define WS_MFT    47164160u   // 38400*256 f32 = 39,321,600 -> ends 86,485,760
#define WS_PLIST  WS_FLAT

typedef float f32x4 __attribute__((ext_vector_type(4)));
typedef __bf16 bf16x8 __attribute__((ext_vector_type(8)));

__device__ __forceinline__ float bf2f(unsigned short u) { return __uint_as_float(((unsigned)u) << 16); }
__device__ __forceinline__ unsigned short f2bf(float f) {
  unsigned b = __float_as_uint(f);
  return (unsigned short)((b + 0x7fffu + ((b >> 16) & 1u)) >> 16);
}
__device__ __forceinline__ unsigned fkey(float f) {
  unsigned b = __float_as_uint(f);
  return b ^ ((b & 0x80000000u) ? 0xFFFFFFFFu : 0x80000000u);
}

// ---------- K1: point-NMS + threshold in LOGIT space ----------
__global__ __launch_bounds__(256) void k_flat(
    const float* __restrict__ c0, const float* __restrict__ c1, const float* __restrict__ c2,
    const float* __restrict__ c3, const float* __restrict__ c4,
    float* __restrict__ flat, unsigned* __restrict__ hist) {
  int idx = blockIdx.x * 256 + threadIdx.x;
  if (idx >= NFLAT) return;
  int s = idx / NCLS, c = idx - s * NCLS;
  const float* base; int g, cell;
  if (s < 1600)      { base = c0; g = 40; cell = s; }
  else if (s < 2896) { base = c1; g = 36; cell = s - 1600; }
  else if (s < 3472) { base = c2; g = 24; cell = s - 2896; }
  else if (s < 3728) { base = c3; g = 16; cell = s - 3472; }
  else               { base = c4; g = 12; cell = s - 3728; }
  int i = cell / g, j = cell - i * g;
  const float* ch = base + c * g * g;
  float x = ch[i * g + j];
  float m = x;
  if (i > 0 && j > 0) m = fmaxf(m, ch[(i - 1) * g + j - 1]);
  if (i > 0)          m = fmaxf(m, ch[(i - 1) * g + j]);
  if (j > 0)          m = fmaxf(m, ch[i * g + j - 1]);
  bool pass = (x >= m) && ((double)x > -2.1972245773362196 /* ln(1/9) */);
  flat[idx] = pass ? x : __int_as_float(0xFF800000);
  if (pass) atomicAdd(&hist[fkey(x) >> 16], 1u);
}

// ---------- K2: pivot ----------
__global__ void k_pivot(const unsigned* __restrict__ hist, unsigned* __restrict__ meta) {
  __shared__ unsigned csum[1024];
  int t = threadIdx.x;
  int hi = 65536 - t * 64, lo = hi - 64;
  unsigned s = 0;
  for (int b = lo; b < hi; ++b) s += hist[b];
  csum[t] = s;
  __syncthreads();
  if (t == 0) {
    unsigned cum = 0;
    for (int cch = 0; cch < 1024; ++cch) {
      if (cum + csum[cch] >= NPRE) {
        int chi = 65536 - cch * 64;
        for (int b = chi - 1; b >= chi - 64; --b) {
          if (cum + hist[b] >= NPRE) { meta[1] = (unsigned)b; return; }
          cum += hist[b];
        }
      }
      cum += csum[cch];
    }
    meta[1] = 0u;
  }
}

// ---------- K3: compact ----------
__global__ __launch_bounds__(256) void k_compact(
    const float* __restrict__ flat, float* __restrict__ cv, int* __restrict__ ci,
    unsigned* __restrict__ meta) {
  int idx = blockIdx.x * 256 + threadIdx.x;
  if (idx >= NFLAT) return;
  float v = flat[idx];
  if (__float_as_uint(v) == 0xFF800000u) return;
  if ((fkey(v) >> 16) >= meta[1]) {
    unsigned pos = atomicAdd(&meta[0], 1u);
    if (pos < 4096u) { cv[pos] = v; ci[pos] = idx; }
  }
}

// ---------- K4: bitonic top-500 select ----------
__global__ __launch_bounds__(1024) void k_select(
    const float* __restrict__ cv, const int* __restrict__ ci, const unsigned* __restrict__ meta,
    double* __restrict__ sel_score, unsigned* __restrict__ sel_grid,
    unsigned* __restrict__ sel_label, double* __restrict__ sel_stride) {
  __shared__ float sv[4096];
  __shared__ int si[4096];
  int t = threadIdx.x;
  int n = (meta[0] < 4096u) ? (int)meta[0] : 4096;
  for (int i = t; i < 4096; i += 1024) {
    if (i < n) { sv[i] = cv[i]; si[i] = ci[i]; }
    else       { sv[i] = __int_as_float(0xFF800000); si[i] = (1 << 30) + i; }
  }
  __syncthreads();
  for (int k = 2; k <= 4096; k <<= 1)
    for (int j = k >> 1; j > 0; j >>= 1) {
      for (int i = t; i < 4096; i += 1024) {
        int ix = i ^ j;
        if (ix > i) {
          float v1 = sv[i], v2 = sv[ix]; int i1 = si[i], i2 = si[ix];
          bool b2 = (v2 > v1) || (v2 == v1 && i2 < i1);
          bool dir = (i & k) == 0;
          if (dir == b2) { sv[i] = v2; sv[ix] = v1; si[i] = i2; si[ix] = i1; }
        }
      }
      __syncthreads();
    }
  for (int i = t; i < NPREP; i += 1024) {
    if (i < NPRE && i < n) {
      int fidx = si[i];
      unsigned gi = (unsigned)fidx / NCLS;
      sel_score[i] = 1.0 / (1.0 + exp(-(double)sv[i]));
      sel_grid[i] = gi;
      sel_label[i] = (unsigned)fidx - gi * NCLS;
      sel_stride[i] = gi < 2896u ? 8.0 : (gi < 3472u ? 16.0 : 32.0);
    } else {
      sel_score[i] = 0.0; sel_grid[i] = 0u; sel_label[i] = 0u; sel_stride[i] = 1e18;
    }
  }
}

// ---------- K5: gather kernel vectors kp[n][k] row-major ----------
__global__ __launch_bounds__(256) void k_gather(
    const float* __restrict__ k0, const float* __restrict__ k1, const float* __restrict__ k2,
    const float* __restrict__ k3, const float* __restrict__ k4,
    const unsigned* __restrict__ sel_grid, float* __restrict__ kp) {
  int tid = blockIdx.x * 256 + threadIdx.x;
  if (tid >= NPREP * NKER) return;
  int n = tid & (NPREP - 1);
  int k = tid >> 9;
  float v = 0.f;
  if (n < NPRE) {
    unsigned gi = sel_grid[n];
    const float* base; unsigned g, cell;
    if (gi < 1600u)      { base = k0; g = 40; cell = gi; }
    else if (gi < 2896u) { base = k1; g = 36; cell = gi - 1600u; }
    else if (gi < 3472u) { base = k2; g = 24; cell = gi - 2896u; }
    else if (gi < 3728u) { base = k3; g = 16; cell = gi - 3472u; }
    else                 { base = k4; g = 12; cell = gi - 3728u; }
    v = base[(unsigned)k * g * g + cell];
  }
  kp[n * NKER + k] = v;
}

// ---------- K6: mf[k][p] -> mfT[p][k] tiled transpose (for coalesced patch) ----------
__global__ __launch_bounds__(256) void k_mft(const float* __restrict__ mf, float* __restrict__ mfT) {
  __shared__ float t[32][33];
  int p0 = blockIdx.x * 32, k0 = blockIdx.y * 32;
  int tx = threadIdx.x & 31, ty = (threadIdx.x >> 5) * 4;
#pragma unroll
  for (int j = 0; j < 4; ++j)
    t[ty + j][tx] = mf[(size_t)(k0 + ty + j) * MP + p0 + tx];
  __syncthreads();
#pragma unroll
  for (int j = 0; j < 4; ++j)
    mfT[(size_t)(p0 + ty + j) * NKER + k0 + tx] = t[tx][ty + j];
}

// ---------- K7: split-bf16 MFMA GEMM (z = al*bh + ah*bl + ah*bh per K32) ----------
// Block 128n x 128p, 4 waves each 64n x 64p (4x4 16x16 tiles), BK=32 -> 8 chunks.
// A frag: m=lane&15 (n-row), k=(lane>>4)*8+j. B frag: n=lane&15 (p-col), same k.
// D (m89-verified): col=lane&15 (p), row=(lane>>4)*4+reg (n).
// Error <= ~3.4e-4 * Sigma|ab|; |z| < TAU=1e-3 entries re-verified fp64 by k_patch.
__global__ __launch_bounds__(256, 2) void k_gemm(
    const float* __restrict__ kp, const float* __restrict__ mf,
    unsigned short* __restrict__ seg, unsigned long long* __restrict__ mb,
    double* __restrict__ part, unsigned* __restrict__ ulist, float* __restrict__ uz,
    unsigned* __restrict__ meta) {
  __shared__ unsigned short AhL[128][40], AlL[128][40];   // padded 80B rows
  __shared__ unsigned short BhL[128][40], BlL[128][40];   // [p][k] after transpose staging
  __shared__ unsigned short bits16[128][8];
  __shared__ double wsumL[128][8];
  int p0 = blockIdx.x * 128, n0 = blockIdx.y * 128;
  int tid = threadIdx.x;
  int lane = tid & 63, w = tid >> 6;
  int wn = w >> 1, wp = w & 1;
  int lg = lane >> 4, ll = lane & 15;
  f32x4 acc[4][4] = {};
  for (int kc = 0; kc < NKER; kc += 32) {
    // stage A from kp[n][k] (row-major, no transpose)
#pragma unroll
    for (int it = 0; it < 4; ++it) {
      int f4 = it * 256 + tid;
      int n = f4 >> 3, kk = (f4 & 7) * 4;
      float4 v = *(const float4*)&kp[(size_t)(n0 + n) * NKER + kc + kk];
      unsigned short h0 = f2bf(v.x), h1 = f2bf(v.y), h2 = f2bf(v.z), h3 = f2bf(v.w);
      ushort4 hv; hv.x = h0; hv.y = h1; hv.z = h2; hv.w = h3;
      ushort4 lv; lv.x = f2bf(v.x - bf2f(h0)); lv.y = f2bf(v.y - bf2f(h1));
      lv.z = f2bf(v.z - bf2f(h2)); lv.w = f2bf(v.w - bf2f(h3));
      *(ushort4*)&AhL[n][kk] = hv;
      *(ushort4*)&AlL[n][kk] = lv;
    }
    // stage B from mf[k][p], transposed to [p][k]
#pragma unroll
    for (int it = 0; it < 4; ++it) {
      int f4 = it * 256 + tid;
      int k = f4 >> 5, pp = (f4 & 31) * 4;
      float4 v = *(const float4*)&mf[(size_t)(kc + k) * MP + p0 + pp];
      float vv[4] = {v.x, v.y, v.z, v.w};
#pragma unroll
      for (int j = 0; j < 4; ++j) {
        unsigned short h = f2bf(vv[j]);
        BhL[pp + j][k] = h;
        BlL[pp + j][k] = f2bf(vv[j] - bf2f(h));
      }
    }
    __syncthreads();
    bf16x8 ah[4], al[4];
#pragma unroll
    for (int tN = 0; tN < 4; ++tN) {
      int nr = wn * 64 + tN * 16 + ll;
      ah[tN] = *(const bf16x8*)&AhL[nr][lg * 8];
      al[tN] = *(const bf16x8*)&AlL[nr][lg * 8];
    }
#pragma unroll
    for (int tP = 0; tP < 4; ++tP) {
      int pr = wp * 64 + tP * 16 + ll;
      bf16x8 bh = *(const bf16x8*)&BhL[pr][lg * 8];
      bf16x8 bl = *(const bf16x8*)&BlL[pr][lg * 8];
#pragma unroll
      for (int tN = 0; tN < 4; ++tN) {
        acc[tN][tP] = __builtin_amdgcn_mfma_f32_16x16x32_bf16(al[tN], bh, acc[tN][tP], 0, 0, 0);
        acc[tN][tP] = __builtin_amdgcn_mfma_f32_16x16x32_bf16(ah[tN], bl, acc[tN][tP], 0, 0, 0);
        acc[tN][tP] = __builtin_amdgcn_mfma_f32_16x16x32_bf16(ah[tN], bh, acc[tN][tP], 0, 0, 0);
      }
    }
    __syncthreads();
  }
  // epilogue: per (tN,tP,r): ballot bits, 16-lane wsum reduce, seg store, uncertain capture
#pragma unroll
  for (int tN = 0; tN < 4; ++tN) {
#pragma unroll
    for (int tP = 0; tP < 4; ++tP) {
#pragma unroll
      for (int r = 0; r < 4; ++r) {
        float z = acc[tN][tP][r];
        bool pos = z > 0.0f;
        unsigned long long bal = __ballot(pos);
        int nloc = wn * 64 + tN * 16 + lg * 4 + r;
        int nn = n0 + nloc;
        float sf = 1.0f / (1.0f + __expf(-z));
        if (nn < NPRE) {
          seg[(size_t)nn * MP + p0 + wp * 64 + tP * 16 + ll] = f2bf(sf);
          if (fabsf(z) < TAU) {
            unsigned q = atomicAdd(&meta[3], 1u);
            if (q < UCAP) {
              int p = p0 + wp * 64 + tP * 16 + ll;
              ulist[q] = ((unsigned)nn << 16) | (unsigned)p;
              uz[q] = z;
            }
          }
        }
        double v = pos ? (double)sf : 0.0;
        v += __shfl_xor(v, 1); v += __shfl_xor(v, 2);
        v += __shfl_xor(v, 4); v += __shfl_xor(v, 8);
        if (ll == 0) {
          bits16[nloc][wp * 4 + tP] = (unsigned short)((bal >> (lg * 16)) & 0xFFFFull);
          wsumL[nloc][wp * 4 + tP] = v;
        }
      }
    }
  }
  __syncthreads();
  if (tid < 128) {
    int nn = n0 + tid;
    if (nn < NPRE) {
      unsigned long long w0 = 0ull, w1 = 0ull;
      double s = 0.0;
#pragma unroll
      for (int tP = 0; tP < 4; ++tP) {
        w0 |= ((unsigned long long)bits16[tid][tP]) << (tP * 16);
        w1 |= ((unsigned long long)bits16[tid][4 + tP]) << (tP * 16);
        s += wsumL[tid][tP] + wsumL[tid][4 + tP];
      }
      int bx = blockIdx.x;
      mb[(size_t)nn * NWORD + bx * 2] = w0;      // identity packing: word bit b <-> p = w*64+b
      mb[(size_t)nn * NWORD + bx * 2 + 1] = w1;
      part[nn * PARTW + bx] = s;
    }
  }
}

// ---------- K8a: fp64 re-verify (coalesced via mfT) ----------
__global__ __launch_bounds__(256) void k_patch_t(
    const float* __restrict__ kp, const float* __restrict__ mfT,
    const unsigned* __restrict__ ulist, const float* __restrict__ uz,
    const unsigned* __restrict__ meta,
    unsigned long long* __restrict__ mb, double* __restrict__ corr) {
  unsigned cnt = meta[3]; if (cnt > UCAP) cnt = UCAP;
  int wid = (blockIdx.x * 256 + threadIdx.x) >> 6;
  int lane = threadIdx.x & 63;
  for (unsigned e = wid; e < cnt; e += 256) {
    unsigned pk = ulist[e];
    int n = (int)(pk >> 16), p = (int)(pk & 0xFFFFu);
    float4 a = *(const float4*)&kp[(size_t)n * NKER + lane * 4];
    float4 b = *(const float4*)&mfT[(size_t)p * NKER + lane * 4];
    double d = 0.0;
    d = fma((double)a.x, (double)b.x, d);
    d = fma((double)a.y, (double)b.y, d);
    d = fma((double)a.z, (double)b.z, d);
    d = fma((double)a.w, (double)b.w, d);
    for (int o = 32; o > 0; o >>= 1) d += __shfl_down(d, o);
    if (lane == 0) {
      float z32 = uz[e];
      bool b32 = z32 > 0.0f;
      bool b64 = d > 0.0;
      if (b32 != b64) {
        atomicXor(&mb[(size_t)n * NWORD + (p >> 6)], 1ull << (p & 63));
        float sf = 1.0f / (1.0f + __expf(-z32));
        atomicAdd(&corr[n], b64 ? (double)sf : -(double)sf);
      }
    }
  }
}

// ---------- K8b: fallback strided patch (if ws too small for mfT) ----------
__global__ __launch_bounds__(256) void k_patch_s(
    const float* __restrict__ kp, const float* __restrict__ mf,
    const unsigned* __restrict__ ulist, const float* __restrict__ uz,
    const unsigned* __restrict__ meta,
    unsigned long long* __restrict__ mb, double* __restrict__ corr) {
  unsigned cnt = meta[3]; if (cnt > UCAP) cnt = UCAP;
  int wid = (blockIdx.x * 256 + threadIdx.x) >> 6;
  int lane = threadIdx.x & 63;
  for (unsigned e = wid; e < cnt; e += 256) {
    unsigned pk = ulist[e];
    int n = (int)(pk >> 16), p = (int)(pk & 0xFFFFu);
    double d = 0.0;
#pragma unroll
    for (int i = 0; i < 4; ++i) {
      int k = lane + 64 * i;
      d = fma((double)kp[n * NKER + k], (double)mf[(size_t)k * MP + p], d);
    }
    for (int o = 32; o > 0; o >>= 1) d += __shfl_down(d, o);
    if (lane == 0) {
      float z32 = uz[e];
      bool b32 = z32 > 0.0f;
      bool b64 = d > 0.0;
      if (b32 != b64) {
        atomicXor(&mb[(size_t)n * NWORD + (p >> 6)], 1ull << (p & 63));
        float sf = 1.0f / (1.0f + __expf(-z32));
        atomicAdd(&corr[n], b64 ? (double)sf : -(double)sf);
      }
    }
  }
}

// ---------- K9: per-instance reduce -> updated score ----------
__global__ void k_masks(const unsigned long long* __restrict__ mb, const double* __restrict__ part,
                        const double* __restrict__ corr,
                        const double* __restrict__ sel_score, const double* __restrict__ sel_stride,
                        double* __restrict__ summask, double* __restrict__ upd) {
  int n = blockIdx.x, t = threadIdx.x;
  int cnt = 0; double ws = 0.0;
  for (int j = t; j < NWORD; j += 64) cnt += __popcll(mb[n * NWORD + j]);
  for (int j = t; j < PARTW; j += 64) ws += part[n * PARTW + j];
  for (int o = 32; o > 0; o >>= 1) { cnt += __shfl_down(cnt, o); ws += __shfl_down(ws, o); }
  if (t == 0) {
    ws += corr[n];
    double cf = (double)cnt;
    double ss = ws / fmax(cf, 1.0);
    double raw = sel_score[n];
    bool keep = (cf > sel_stride[n]) && (raw > 0.0);
    summask[n] = cf;
    upd[n] = keep ? raw * ss : 0.0;
  }
}

// ---------- K10: stable descending fp64 sort + pair list ----------
__global__ __launch_bounds__(512) void k_sort(
    const double* __restrict__ upd, const unsigned* __restrict__ sel_label, const double* __restrict__ summask,
    double* __restrict__ s_score, unsigned* __restrict__ s_slot, unsigned* __restrict__ s_label2,
    double* __restrict__ s_sum, unsigned* __restrict__ plist, unsigned* __restrict__ meta) {
  __shared__ double sv[NPREP];
  __shared__ int si[NPREP];
  __shared__ unsigned labv[NPREP];
  int t = threadIdx.x;
  sv[t] = (t < NPRE) ? upd[t] : -1.0;
  si[t] = t;
  __syncthreads();
  for (int k = 2; k <= NPREP; k <<= 1)
    for (int j = k >> 1; j > 0; j >>= 1) {
      int ix = t ^ j;
      if (ix > t) {
        double v1 = sv[t], v2 = sv[ix]; int i1 = si[t], i2 = si[ix];
        bool b2 = (v2 > v1) || (v2 == v1 && i2 < i1);
        bool dir = (t & k) == 0;
        if (dir == b2) { sv[t] = v2; sv[ix] = v1; si[t] = i2; si[ix] = i1; }
      }
      __syncthreads();
    }
  double sc = sv[t]; int slot = si[t];
  bool alive = sc > 0.0;
  unsigned lab = sel_label[slot];
  s_score[t] = alive ? sc : 0.0;
  s_slot[t] = (unsigned)slot;
  s_label2[t] = lab;
  s_sum[t] = (alive && slot < NPRE) ? summask[slot] : 0.0;
  labv[t] = alive ? lab : (0x10000u + (unsigned)t);
  __syncthreads();
  if (t < NPRE) {
    unsigned li = labv[t];
    if (li < 0x10000u) {
      for (int j = t + 1; j < NPRE; ++j) {
        if (labv[j] == li) {
          unsigned pos = atomicAdd(&meta[2], 1u);
          plist[pos] = ((unsigned)t << 16) | (unsigned)j;
        }
      }
    }
  }
}

// ---------- K11: per-pair IoU + atomicMax compS[j] ----------
__global__ __launch_bounds__(256) void k_inter(
    const unsigned long long* __restrict__ mb, const unsigned* __restrict__ s_slot,
    const double* __restrict__ s_sum, const unsigned* __restrict__ plist,
    const unsigned* __restrict__ meta, double* __restrict__ piou,
    unsigned long long* __restrict__ cmp_bits) {
  int wid = (blockIdx.x * 256 + threadIdx.x) >> 6;
  int lane = threadIdx.x & 63;
  unsigned npair = meta[2];
  for (unsigned pp = wid; pp < npair; pp += 256) {
    unsigned pk = plist[pp];
    int i = (int)(pk >> 16), j = (int)(pk & 0xFFFFu);
    const unsigned long long* A = mb + (size_t)s_slot[i] * NWORD;
    const unsigned long long* B = mb + (size_t)s_slot[j] * NWORD;
    int c = 0;
    for (int wd = lane; wd < NWORD; wd += 64) c += __popcll(A[wd] & B[wd]);
    for (int o = 32; o > 0; o >>= 1) c += __shfl_down(c, o);
    if (lane == 0) {
      double inter = (double)c;
      double uni = s_sum[i] + s_sum[j] - inter;
      double val = (uni > 0.0) ? inter / fmax(uni, 1.0) : 0.0;
      piou[pp] = val;
      if (val > 0.0)
        atomicMax(&cmp_bits[j], (unsigned long long)__double_as_longlong(val));
    }
  }
}

// ---------- K12: fused decay-max + threshold + stable top-100 ----------
__global__ __launch_bounds__(512) void k_top(
    const unsigned* __restrict__ plist, const unsigned* __restrict__ meta,
    const double* __restrict__ piou, const unsigned long long* __restrict__ cmp_bits,
    const double* __restrict__ s_score, const unsigned* __restrict__ s_label2,
    const unsigned* __restrict__ s_slot,
    float* __restrict__ d_out, int maskN, unsigned* __restrict__ up_slot) {
  __shared__ unsigned long long mS[NPREP];
  __shared__ double sv[NPREP];
  __shared__ int si[NPREP];
  int t = threadIdx.x;
  mS[t] = 0ull;
  __syncthreads();
  unsigned npair = meta[2];
  for (unsigned p = t; p < npair; p += NPREP) {
    unsigned pk = plist[p];
    int i = (int)(pk >> 16), j = (int)(pk & 0xFFFFu);
    double d = piou[p];
    double ci = __longlong_as_double((long long)cmp_bits[i]);
    double v = d * d - ci * ci;
    if (v > 0.0)
      atomicMax(&mS[j], (unsigned long long)__double_as_longlong(v));
  }
  __syncthreads();
  double f = 0.0;
  if (t < NPRE) {
    double m = __longlong_as_double((long long)mS[t]);
    f = s_score[t] * exp(-2.0 * m);
    if (f < 0.05) f = 0.0;
  }
  sv[t] = f; si[t] = t;
  __syncthreads();
  for (int k = 2; k <= NPREP; k <<= 1)
    for (int j = k >> 1; j > 0; j >>= 1) {
      int ix = t ^ j;
      if (ix > t) {
        double v1 = sv[t], v2 = sv[ix]; int i1 = si[t], i2 = si[ix];
        bool b2 = (v2 > v1) || (v2 == v1 && i2 < i1);
        bool dir = (t & k) == 0;
        if (dir == b2) { sv[t] = v2; sv[ix] = v1; si[t] = i2; si[ix] = i1; }
      }
      __syncthreads();
    }
  if (t < MAXI) {
    int pos = si[t];
    d_out[maskN + t] = (float)sv[t];
    d_out[maskN + MAXI + t] = (float)s_label2[pos];
    up_slot[t] = s_slot[pos];
  }
}

// ---------- K13: 4x bilinear upsample, 4 px/thread ----------
__global__ __launch_bounds__(256) void k_up(const unsigned short* __restrict__ seg,
                                            const unsigned* __restrict__ up_slot,
                                            float* __restrict__ out, int maskN) {
  int o4 = (blockIdx.x * 256 + threadIdx.x) * 4;
  if (o4 >= maskN) return;
  int m = o4 / (OH * OW);
  int rem = o4 - m * (OH * OW);
  int y = rem / OW;
  int x = rem - y * OW;
  int a = x >> 2;
  const unsigned short* row = seg + (size_t)up_slot[m] * MP;
  float sy = y * 0.25f - 0.375f;
  int y0 = (int)floorf(sy);
  float wy = sy - y0;
  int y0c = max(y0, 0), y1c = min(y0 + 1, MH - 1);
  const unsigned short* r0 = row + y0c * MW;
  const unsigned short* r1 = row + y1c * MW;
  int t0 = max(a - 1, 0), t1 = a, t2 = min(a + 1, MW - 1);
  float T0 = bf2f(r0[t0]), T1 = bf2f(r0[t1]), T2 = bf2f(r0[t2]);
  float B0 = bf2f(r1[t0]), B1 = bf2f(r1[t1]), B2 = bf2f(r1[t2]);
  float iwy = 1.f - wy;
  float4 o;
  o.x = iwy * (0.375f * T0 + 0.625f * T1) + wy * (0.375f * B0 + 0.625f * B1);
  o.y = iwy * (0.125f * T0 + 0.875f * T1) + wy * (0.125f * B0 + 0.875f * B1);
  o.z = iwy * (0.875f * T1 + 0.125f * T2) + wy * (0.875f * B1 + 0.125f * B2);
  o.w = iwy * (0.625f * T1 + 0.375f * T2) + wy * (0.625f * B1 + 0.375f * B2);
  o.x = (o.x > 0.5f) ? 1.f : 0.f;
  o.y = (o.y > 0.5f) ? 1.f : 0.f;
  o.z = (o.z > 0.5f) ? 1.f : 0.f;
  o.w = (o.w > 0.5f) ? 1.f : 0.f;
  *(float4*)&out[o4] = o;
}

extern "C" void kernel_launch(void* const* d_in, const int* in_sizes, int n_in,
                              void* d_out, int out_size, void* d_ws, size_t ws_size,
                              hipStream_t stream) {
  // setup_inputs() dict order is INTERLEAVED: cate_p0, kern_p0, cate_p1, kern_p1, ...
  const float* c0 = (const float*)d_in[0];
  const float* k0 = (const float*)d_in[1];
  const float* c1 = (const float*)d_in[2];
  const float* k1 = (const float*)d_in[3];
  const float* c2 = (const float*)d_in[4];
  const float* k2 = (const float*)d_in[5];
  const float* c3 = (const float*)d_in[6];
  const float* k3 = (const float*)d_in[7];
  const float* c4 = (const float*)d_in[8];
  const float* k4 = (const float*)d_in[9];
  const float* mf = (const float*)d_in[10];

  char* ws = (char*)d_ws;
  unsigned* hist = (unsigned*)(ws + WS_HIST);
  unsigned* meta = (unsigned*)(ws + WS_META);
  unsigned long long* cmp_bits = (unsigned long long*)(ws + WS_CMP);
  double* corr = (double*)(ws + WS_CORR);
  double* piou = (double*)(ws + WS_PIOU);
  float* cv = (float*)(ws + WS_CANDV);
  int* ci = (int*)(ws + WS_CANDI);
  float* flat = (float*)(ws + WS_FLAT);
  float* kp = (float*)(ws + WS_KP);
  double* sel_score  = (double*)(ws + WS_SEL + 0);
  unsigned* sel_grid = (unsigned*)(ws + WS_SEL + 4096);
  unsigned* sel_label= (unsigned*)(ws + WS_SEL + 8192);
  double* sel_stride = (double*)(ws + WS_SEL + 12288);
  double* upd        = (double*)(ws + WS_SEL + 16384);
  double* summask    = (double*)(ws + WS_SEL + 20480);
  double* s_score    = (double*)(ws + WS_SEL + 24576);
  unsigned* s_slot   = (unsigned*)(ws + WS_SEL + 28672);
  unsigned* s_label2 = (unsigned*)(ws + WS_SEL + 32768);
  double* s_sum      = (double*)(ws + WS_SEL + 36864);
  unsigned* up_slot  = (unsigned*)(ws + WS_SEL + 49152);
  unsigned long long* mb = (unsigned long long*)(ws + WS_MB);
  double* part = (double*)(ws + WS_PART);
  unsigned short* seg = (unsigned short*)(ws + WS_SEG);
  unsigned* plist = (unsigned*)(ws + WS_PLIST);
  unsigned* ulist = (unsigned*)(ws + WS_ULIST);
  float* uzp = (float*)(ws + WS_UZ);
  float* mfT = (float*)(ws + WS_MFT);

  int maskN = out_size - 2 * MAXI;  // 100*640*960
  bool use_mft = ws_size >= (size_t)WS_MFT + (size_t)MP * NKER * 4;

  hipMemsetAsync(ws, 0, WS_ZEROB, stream);  // hist + meta + cmp_bits + corr

  k_flat<<<(NFLAT + 255) / 256, 256, 0, stream>>>(c0, c1, c2, c3, c4, flat, hist);
  k_pivot<<<1, 1024, 0, stream>>>(hist, meta);
  k_compact<<<(NFLAT + 255) / 256, 256, 0, stream>>>(flat, cv, ci, meta);
  k_select<<<1, 1024, 0, stream>>>(cv, ci, meta, sel_score, sel_grid, sel_label, sel_stride);
  k_gather<<<(NPREP * NKER + 255) / 256, 256, 0, stream>>>(k0, k1, k2, k3, k4, sel_grid, kp);
  if (use_mft)
    k_mft<<<dim3(MP / 32, NKER / 32), 256, 0, stream>>>(mf, mfT);
  dim3 g6(MP / 128, NPREP / 128);  // 300 x 4
  k_gemm<<<g6, 256, 0, stream>>>(kp, mf, seg, mb, part, ulist, uzp, meta);
  if (use_mft)
    k_patch_t<<<64, 256, 0, stream>>>(kp, mfT, ulist, uzp, meta, mb, corr);
  else
    k_patch_s<<<64, 256, 0, stream>>>(kp, mf, ulist, uzp, meta, mb, corr);
  k_masks<<<NPRE, 64, 0, stream>>>(mb, part, corr, sel_score, sel_stride, summask, upd);
  k_sort<<<1, NPREP, 0, stream>>>(upd, sel_label, summask, s_score, s_slot, s_label2, s_sum, plist, meta);
  k_inter<<<64, 256, 0, stream>>>(mb, s_slot, s_sum, plist, meta, piou, cmp_bits);
  k_top<<<1, NPREP, 0, stream>>>(plist, meta, piou, cmp_bits, s_score, s_label2, s_slot,
                                 (float*)d_out, maskN, up_slot);
  k_up<<<(maskN / 4 + 255) / 256, 256, 0, stream>>>(seg, up_slot, (float*)d_out, maskN);
}